// Round 11
// baseline (360.816 us; speedup 1.0000x reference)
//
#include <hip/hip_runtime.h>
#include <hip/hip_bf16.h>

#define N_NODES 100000
#define N_EDGES 600000
#define NB      512
#define H       128
#define ED      8
#define SCAN_CHUNK 1024
#define N_CHUNKS   98   // 98*1024 = 100352 >= N_NODES+1

typedef __attribute__((ext_vector_type(8))) short short8;
typedef __attribute__((ext_vector_type(4))) float f32x4;
typedef __attribute__((ext_vector_type(4))) unsigned int u32x4;
typedef unsigned short u16;
typedef unsigned int   u32;

static __device__ __forceinline__ u16 f2bf(float f) {
    u32 u = __float_as_uint(f);
    u32 r = u + 0x7fffu + ((u >> 16) & 1u);
    return (u16)(r >> 16);
}
static __device__ __forceinline__ float bf2f(u32 h) {
    return __uint_as_float(h << 16);
}
// packed f32->bf16 (RNE, same as f2bf): lo->bits[15:0], hi->bits[31:16]
static __device__ __forceinline__ u32 bfpack(float lo, float hi) {
    u32 r;
    asm("v_cvt_pk_bf16_f32 %0, %1, %2" : "=v"(r) : "v"(lo), "v"(hi));
    return r;
}

// ---- fused: weight pack (0..49) + hist (50..2393) + zero sums (2394..2458)
__global__ __launch_bounds__(256) void pack_hist_kernel(
    const float* __restrict__ W0, const float* __restrict__ W1,
    const float* __restrict__ W2, const float* __restrict__ W3,
    const float* __restrict__ W4, const float* __restrict__ W5,
    const float* __restrict__ W6,
    short8* __restrict__ O0, short8* __restrict__ O1,
    short8* __restrict__ O2, short8* __restrict__ O3,
    short8* __restrict__ O4, short8* __restrict__ O5,
    short8* __restrict__ O6,
    const int* __restrict__ edge_index, int* __restrict__ counts,
    uint4* __restrict__ sums_zero)
{
    const int HIST_BLKS = (N_EDGES + 255) / 256;   // 2344
    if (blockIdx.x >= 50 + HIST_BLKS) {
        // zero sums_buf + cnt_buf: 264,192 B = 16512 uint4
        int idx = (blockIdx.x - 50 - HIST_BLKS) * 256 + threadIdx.x;
        if (idx < 16512) sums_zero[idx] = make_uint4(0, 0, 0, 0);
        return;
    }
    if (blockIdx.x >= 50) {
        int e = (blockIdx.x - 50) * 256 + threadIdx.x;
        if (e < N_EDGES) atomicAdd(&counts[edge_index[N_EDGES + e]], 1);
        return;
    }
    int gid = blockIdx.x * 256 + threadIdx.x;   // < 12800 exactly
    const float* W; short8* O; int Krows, kkmax, slot;
    if (gid < 512) { W = W0; O = O0; Krows = ED; kkmax = 1; slot = gid; }
    else {
        int m = (gid - 512) / 2048;
        slot = (gid - 512) % 2048;
        Krows = H; kkmax = 4;
        switch (m) {
            case 0: W = W1; O = O1; break;
            case 1: W = W2; O = O2; break;
            case 2: W = W3; O = O3; break;
            case 3: W = W4; O = O4; break;
            case 4: W = W5; O = O5; break;
            default: W = W6; O = O6; break;
        }
    }
    int lane = slot & 63;
    int t = slot >> 6;
    int nt = t & 1; t >>= 1;
    int kk = t % kkmax;
    int w  = t / kkmax;
    int quad = lane >> 4, n15 = lane & 15;
    int n = w * 32 + nt * 16 + n15;
    short8 v;
    #pragma unroll
    for (int j = 0; j < 8; j++) {
        int k = kk * 32 + quad * 8 + j;
        v[j] = (k < Krows) ? (short)f2bf(W[k * H + n]) : (short)0;
    }
    O[slot] = v;
}

// ---- fused: per-chunk scan (blocks 0..97) + node MLP (1 tile/block) -------
__global__ __launch_bounds__(256) void scan_node_kernel(
    const int* __restrict__ counts, int* __restrict__ chunk_scan,
    int* __restrict__ bsum_raw,
    const int* __restrict__ ids,
    const float* __restrict__ w1, const float* __restrict__ b1,
    const short8* __restrict__ pW2, const float* __restrict__ b2,
    u16* __restrict__ x_out)
{
    __shared__ u16 sH[64 * 136];
    __shared__ float s_x0[64];
    __shared__ int sS[256];
    int tid = threadIdx.x;

    if (blockIdx.x < N_CHUNKS) {
        // ---- scan1: 1024-elem chunk, 4 elems/thread ----
        int base = blockIdx.x * SCAN_CHUNK + tid * 4;
        int4 v = *(const int4*)&counts[base];
        int q0 = v.x, q1 = q0 + v.y, q2 = q1 + v.z, q3 = q2 + v.w;
        sS[tid] = q3;
        __syncthreads();
        #pragma unroll
        for (int off = 1; off < 256; off <<= 1) {
            int t = (tid >= off) ? sS[tid - off] : 0;
            __syncthreads();
            sS[tid] += t;
            __syncthreads();
        }
        int excl = sS[tid] - q3;
        int4 o;
        o.x = excl; o.y = excl + q0; o.z = excl + q1; o.w = excl + q2;
        *(int4*)&chunk_scan[base] = o;
        if (tid == 255) bsum_raw[blockIdx.x] = sS[255];
        return;
    }

    // ---- node MLP on blocks 98..1660 (1563 blocks, 1 tile each) ----
    int bid = blockIdx.x - N_CHUNKS;
    int w = tid >> 6, lane = tid & 63, quad = lane >> 4, n15 = lane & 15;
    short8 fW2[4][2];
    #pragma unroll
    for (int kk = 0; kk < 4; kk++) {
        fW2[kk][0] = pW2[((w * 4 + kk) * 2 + 0) * 64 + lane];
        fW2[kk][1] = pW2[((w * 4 + kk) * 2 + 1) * 64 + lane];
    }
    float rb2[2] = { b2[w * 32 + n15], b2[w * 32 + 16 + n15] };
    float w1c = w1[tid & 127], b1c = b1[tid & 127];
    const int ntile = (N_NODES + 63) / 64;   // 1563
    for (int tile = bid; tile < ntile; tile += 1563) {
        int row0 = tile * 64;
        if (tid < 64) {
            int n = row0 + tid;
            float x0 = (n < N_NODES) ? (float)ids[n] / 281474976710655.0f : 0.0f;
            s_x0[tid] = fminf(fmaxf(x0, 0.0f), 1.0f);
        }
        __syncthreads();
        int half = tid >> 7, c = tid & 127;
        #pragma unroll
        for (int rr = 0; rr < 32; rr += 2) {
            int r = half + rr * 2;
            u32 p = bfpack(fmaxf(s_x0[r] * w1c + b1c, 0.0f),
                           fmaxf(s_x0[r + 2] * w1c + b1c, 0.0f));
            sH[r * 136 + c]       = (u16)p;
            sH[(r + 2) * 136 + c] = (u16)(p >> 16);
        }
        __syncthreads();
        f32x4 acc[4][2];
        #pragma unroll
        for (int s = 0; s < 4; s++) { acc[s][0] = (f32x4){0,0,0,0}; acc[s][1] = (f32x4){0,0,0,0}; }
        #pragma unroll
        for (int kk = 0; kk < 4; kk++) {
            #pragma unroll
            for (int s = 0; s < 4; s++) {
                short8 a = *(const short8*)&sH[(s * 16 + n15) * 136 + kk * 32 + quad * 8];
                acc[s][0] = __builtin_amdgcn_mfma_f32_16x16x32_bf16(a, fW2[kk][0], acc[s][0], 0, 0, 0);
                acc[s][1] = __builtin_amdgcn_mfma_f32_16x16x32_bf16(a, fW2[kk][1], acc[s][1], 0, 0, 0);
            }
        }
        __syncthreads();
        #pragma unroll
        for (int s = 0; s < 4; s++)
            #pragma unroll
            for (int nt = 0; nt < 2; nt++) {
                int col = w * 32 + nt * 16 + n15;
                int rb = (s * 16 + quad * 4) * 136 + col;
                u32 p0 = bfpack(acc[s][nt][0] + rb2[nt], acc[s][nt][1] + rb2[nt]);
                u32 p1 = bfpack(acc[s][nt][2] + rb2[nt], acc[s][nt][3] + rb2[nt]);
                sH[rb]       = (u16)p0;
                sH[rb + 136] = (u16)(p0 >> 16);
                sH[rb + 272] = (u16)p1;
                sH[rb + 408] = (u16)(p1 >> 16);
            }
        __syncthreads();
        for (int idx = tid; idx < 64 * 16; idx += 256) {
            int r = idx >> 4, c8 = (idx & 15) << 3;
            int n = row0 + r;
            if (n < N_NODES)
                *(uint4*)&x_out[(long)n * H + c8] = *(const uint4*)&sH[r * 136 + c8];
        }
        __syncthreads();
    }
}

// ---- fill (+local 98-chunk scan, replaces scan2 dispatch) -----------------
__global__ __launch_bounds__(256) void fill_kernel(
    const int* __restrict__ edge_index,
    const int* __restrict__ chunk_scan, const int* __restrict__ bsum_raw,
    int* __restrict__ counts, int* __restrict__ src_list,
    const float* __restrict__ attr, u16* __restrict__ attr_perm)
{
    __shared__ int sB[128];
    int tid = threadIdx.x;
    int v0 = 0;
    if (tid < 128) {
        v0 = (tid < N_CHUNKS) ? bsum_raw[tid] : 0;
        sB[tid] = v0;
    }
    __syncthreads();
    #pragma unroll
    for (int off = 1; off < 128; off <<= 1) {
        int t = (tid < 128 && tid >= off) ? sB[tid - off] : 0;
        __syncthreads();
        if (tid < 128) sB[tid] += t;
        __syncthreads();
    }
    if (tid < 128) sB[tid] -= v0;   // exclusive
    __syncthreads();

    int e = blockIdx.x * 256 + tid;
    if (e >= N_EDGES) return;
    int src = edge_index[e];
    int dst = edge_index[N_EDGES + e];
    int slot = atomicAdd(&counts[dst], -1) - 1;
    int pos = chunk_scan[dst] + sB[dst >> 10] + slot;
    src_list[pos] = src;
    float4 a0 = *(const float4*)&attr[(long)e * ED];
    float4 a1 = *(const float4*)&attr[(long)e * ED + 4];
    u32 w0 = bfpack(a0.x, a0.y);
    u32 w1 = bfpack(a0.z, a0.w);
    u32 w2 = bfpack(a1.x, a1.y);
    u32 w3 = bfpack(a1.z, a1.w);
    *(uint4*)&attr_perm[(long)pos * ED] = make_uint4(w0, w1, w2, w3);
}

// ---- edge MLP v3 (+finalize row_start prologue on blocks 0..391) ----------
__global__ __launch_bounds__(256) void edge_mlp_mfma(
    const u16* __restrict__ attr_perm,
    const int* __restrict__ chunk_scan, const int* __restrict__ bsum_raw,
    int* __restrict__ row_start,
    const short8* __restrict__ pW1, const float* __restrict__ b1,
    const short8* __restrict__ pW2, const float* __restrict__ b2,
    u16* __restrict__ e_perm)
{
    __shared__ u16 sH[64 * 136];
    __shared__ int sB[128];
    int tid = threadIdx.x;

    if (blockIdx.x < 392) {   // finalize: row_start[i] = chunk_scan[i]+bsum[i>>10]
        int v0 = 0;
        if (tid < 128) {
            v0 = (tid < N_CHUNKS) ? bsum_raw[tid] : 0;
            sB[tid] = v0;
        }
        __syncthreads();
        #pragma unroll
        for (int off = 1; off < 128; off <<= 1) {
            int t = (tid < 128 && tid >= off) ? sB[tid - off] : 0;
            __syncthreads();
            if (tid < 128) sB[tid] += t;
            __syncthreads();
        }
        if (tid < 128) sB[tid] -= v0;
        __syncthreads();
        int i = blockIdx.x * 256 + tid;   // 392*256 = 100352 >= N_NODES+1
        if (i <= N_NODES) row_start[i] = chunk_scan[i] + sB[i >> 10];
        __syncthreads();
    }

    int w = tid >> 6, lane = tid & 63, quad = lane >> 4, n15 = lane & 15;
    short8 fW1[2];
    fW1[0] = pW1[(w * 2 + 0) * 64 + lane];
    fW1[1] = pW1[(w * 2 + 1) * 64 + lane];
    short8 fW2[4][2];
    #pragma unroll
    for (int kk = 0; kk < 4; kk++) {
        fW2[kk][0] = pW2[((w * 4 + kk) * 2 + 0) * 64 + lane];
        fW2[kk][1] = pW2[((w * 4 + kk) * 2 + 1) * 64 + lane];
    }
    float rb1[2] = { b1[w * 32 + n15], b1[w * 32 + 16 + n15] };
    float rb2[2] = { b2[w * 32 + n15], b2[w * 32 + 16 + n15] };
    const short8 zero8 = (short8){0,0,0,0,0,0,0,0};
    const int ntile = N_EDGES / 64;   // 9375 exact = 3 * 3125
    for (int tile = blockIdx.x; tile < ntile; tile += gridDim.x) {
        int row0 = tile * 64;
        short8 av[4];
        #pragma unroll
        for (int s = 0; s < 4; s++) {
            av[s] = zero8;
            if (quad == 0)
                av[s] = *(const short8*)&attr_perm[(long)(row0 + s * 16 + n15) * ED];
        }
        // GEMM1 (K=32, one step)
        f32x4 acc[4][2];
        #pragma unroll
        for (int s = 0; s < 4; s++) { acc[s][0] = (f32x4){0,0,0,0}; acc[s][1] = (f32x4){0,0,0,0}; }
        #pragma unroll
        for (int s = 0; s < 4; s++) {
            acc[s][0] = __builtin_amdgcn_mfma_f32_16x16x32_bf16(av[s], fW1[0], acc[s][0], 0, 0, 0);
            acc[s][1] = __builtin_amdgcn_mfma_f32_16x16x32_bf16(av[s], fW1[1], acc[s][1], 0, 0, 0);
        }
        #pragma unroll
        for (int s = 0; s < 4; s++)
            #pragma unroll
            for (int nt = 0; nt < 2; nt++) {
                int col = w * 32 + nt * 16 + n15;
                int rb = (s * 16 + quad * 4) * 136 + col;
                u32 p0 = bfpack(fmaxf(acc[s][nt][0] + rb1[nt], 0.0f),
                                fmaxf(acc[s][nt][1] + rb1[nt], 0.0f));
                u32 p1 = bfpack(fmaxf(acc[s][nt][2] + rb1[nt], 0.0f),
                                fmaxf(acc[s][nt][3] + rb1[nt], 0.0f));
                sH[rb]       = (u16)p0;
                sH[rb + 136] = (u16)(p0 >> 16);
                sH[rb + 272] = (u16)p1;
                sH[rb + 408] = (u16)(p1 >> 16);
            }
        __syncthreads();
        // GEMM2 (K=128)
        #pragma unroll
        for (int s = 0; s < 4; s++) { acc[s][0] = (f32x4){0,0,0,0}; acc[s][1] = (f32x4){0,0,0,0}; }
        #pragma unroll
        for (int kk = 0; kk < 4; kk++) {
            #pragma unroll
            for (int s = 0; s < 4; s++) {
                short8 a = *(const short8*)&sH[(s * 16 + n15) * 136 + kk * 32 + quad * 8];
                acc[s][0] = __builtin_amdgcn_mfma_f32_16x16x32_bf16(a, fW2[kk][0], acc[s][0], 0, 0, 0);
                acc[s][1] = __builtin_amdgcn_mfma_f32_16x16x32_bf16(a, fW2[kk][1], acc[s][1], 0, 0, 0);
            }
        }
        __syncthreads();
        #pragma unroll
        for (int s = 0; s < 4; s++)
            #pragma unroll
            for (int nt = 0; nt < 2; nt++) {
                int col = w * 32 + nt * 16 + n15;
                int rb = (s * 16 + quad * 4) * 136 + col;
                u32 p0 = bfpack(acc[s][nt][0] + rb2[nt], acc[s][nt][1] + rb2[nt]);
                u32 p1 = bfpack(acc[s][nt][2] + rb2[nt], acc[s][nt][3] + rb2[nt]);
                sH[rb]       = (u16)p0;
                sH[rb + 136] = (u16)(p0 >> 16);
                sH[rb + 272] = (u16)p1;
                sH[rb + 408] = (u16)(p1 >> 16);
            }
        __syncthreads();
        for (int idx = tid; idx < 64 * 16; idx += 256) {
            int r = idx >> 4, c8 = (idx & 15) << 3;
            *(uint4*)&e_perm[(long)(row0 + r) * H + c8] = *(const uint4*)&sH[r * 136 + c8];
        }
        __syncthreads();
    }
}

// ---- fused GINE layer: barrier-free gather + 16-row conv (+opt. pool) -----
static __device__ __forceinline__ void acc8(float* a, u32x4 xv, u32x4 ev) {
    #pragma unroll
    for (int q = 0; q < 4; q++) {
        a[2 * q + 0] += fmaxf(bf2f(xv[q] & 0xffff) + bf2f(ev[q] & 0xffff), 0.0f);
        a[2 * q + 1] += fmaxf(bf2f(xv[q] >> 16)    + bf2f(ev[q] >> 16),    0.0f);
    }
}

__global__ __launch_bounds__(256) void gine_fused(
    const int* __restrict__ row_start,
    const int* __restrict__ src_list,
    const u16* __restrict__ e_perm,
    const u16* __restrict__ x,
    const short8* __restrict__ pW1, const float* __restrict__ b1,
    const short8* __restrict__ pW2, const float* __restrict__ b2,
    u16* __restrict__ x_out,
    const int* __restrict__ batch, float* __restrict__ sums,
    float* __restrict__ cnt, int do_pool)
{
    __shared__ u16 sA[16 * 136];
    __shared__ int sBt[16];
    int tid  = threadIdx.x;
    int lane = tid & 63;
    int l16  = lane & 15;
    int base = lane & 48;            // group base lane within wave
    int fo   = l16 * 8;              // 8 u16 cols per lane
    int r    = tid >> 4;             // local row 0..15
    int n    = blockIdx.x * 16 + r;  // exact: 6250*16 = 100000
    const u16* xb = x + fo;

    if (do_pool && tid < 16) sBt[tid] = batch[blockIdx.x * 16 + tid];

    // ---------- gather phase (no barriers) ----------
    int beg = row_start[n];
    int end = row_start[n + 1];
    float a[8], b[8];
    #pragma unroll
    for (int q = 0; q < 8; q++) { a[q] = 0.0f; b[q] = 0.0f; }

    for (int j0 = beg; j0 < end; j0 += 16) {
        int m = min(16, end - j0);
        int sv = src_list[j0 + min(l16, m - 1)];
        const u16* ej = e_perm + (long)j0 * H + fo;
        int j = 0;
        for (; j + 2 <= m; j += 2) {
            int s0 = __shfl(sv, base | j);
            int s1 = __shfl(sv, base | (j + 1));
            u32x4 xv0 = *(const u32x4*)(xb + (long)s0 * H);
            u32x4 ev0 = *(const u32x4*)(ej + (long)(j + 0) * H);
            u32x4 xv1 = *(const u32x4*)(xb + (long)s1 * H);
            u32x4 ev1 = *(const u32x4*)(ej + (long)(j + 1) * H);
            acc8(a, xv0, ev0);
            acc8(b, xv1, ev1);
        }
        if (j < m) {
            int s0 = __shfl(sv, base | j);
            u32x4 xv0 = *(const u32x4*)(xb + (long)s0 * H);
            u32x4 ev0 = *(const u32x4*)(ej + (long)j * H);
            acc8(a, xv0, ev0);
        }
    }
    u32x4 xself = *(const u32x4*)(xb + (long)n * H);
    u32x4 xsrow;
    #pragma unroll
    for (int q = 0; q < 4; q++) {
        float o0 = bf2f(xself[q] & 0xffff) + a[2 * q + 0] + b[2 * q + 0];
        float o1 = bf2f(xself[q] >> 16)    + a[2 * q + 1] + b[2 * q + 1];
        xsrow[q] = bfpack(o0, o1);
    }
    *(uint4*)&sA[r * 136 + fo] = *(uint4*)&xsrow;   // xs row -> LDS (bf16)
    __syncthreads();

    // ---------- conv phase: 16x128 tile, 2 GEMMs ----------
    int w = tid >> 6, quad = lane >> 4, n15 = l16;
    float rb1[2] = { b1[w * 32 + n15], b1[w * 32 + 16 + n15] };
    float rb2[2] = { b2[w * 32 + n15], b2[w * 32 + 16 + n15] };
    // GEMM1 (weights streamed from global/L2 to keep VGPR low)
    f32x4 acc[2];
    acc[0] = (f32x4){0,0,0,0}; acc[1] = (f32x4){0,0,0,0};
    #pragma unroll
    for (int kk = 0; kk < 4; kk++) {
        short8 av = *(const short8*)&sA[n15 * 136 + kk * 32 + quad * 8];
        short8 w0 = pW1[((w * 4 + kk) * 2 + 0) * 64 + lane];
        short8 w1v = pW1[((w * 4 + kk) * 2 + 1) * 64 + lane];
        acc[0] = __builtin_amdgcn_mfma_f32_16x16x32_bf16(av, w0, acc[0], 0, 0, 0);
        acc[1] = __builtin_amdgcn_mfma_f32_16x16x32_bf16(av, w1v, acc[1], 0, 0, 0);
    }
    __syncthreads();   // sA reads done
    #pragma unroll
    for (int nt = 0; nt < 2; nt++) {
        int col = w * 32 + nt * 16 + n15;
        int rb = (quad * 4) * 136 + col;
        u32 p0 = bfpack(fmaxf(acc[nt][0] + rb1[nt], 0.0f),
                        fmaxf(acc[nt][1] + rb1[nt], 0.0f));
        u32 p1 = bfpack(fmaxf(acc[nt][2] + rb1[nt], 0.0f),
                        fmaxf(acc[nt][3] + rb1[nt], 0.0f));
        sA[rb]       = (u16)p0;
        sA[rb + 136] = (u16)(p0 >> 16);
        sA[rb + 272] = (u16)p1;
        sA[rb + 408] = (u16)(p1 >> 16);
    }
    __syncthreads();
    // GEMM2
    acc[0] = (f32x4){0,0,0,0}; acc[1] = (f32x4){0,0,0,0};
    #pragma unroll
    for (int kk = 0; kk < 4; kk++) {
        short8 av = *(const short8*)&sA[n15 * 136 + kk * 32 + quad * 8];
        short8 w0 = pW2[((w * 4 + kk) * 2 + 0) * 64 + lane];
        short8 w1v = pW2[((w * 4 + kk) * 2 + 1) * 64 + lane];
        acc[0] = __builtin_amdgcn_mfma_f32_16x16x32_bf16(av, w0, acc[0], 0, 0, 0);
        acc[1] = __builtin_amdgcn_mfma_f32_16x16x32_bf16(av, w1v, acc[1], 0, 0, 0);
    }
    __syncthreads();   // sA reads done
    #pragma unroll
    for (int nt = 0; nt < 2; nt++) {
        int col = w * 32 + nt * 16 + n15;
        int rb = (quad * 4) * 136 + col;
        u32 p0 = bfpack(fmaxf(acc[nt][0] + rb2[nt], 0.0f),
                        fmaxf(acc[nt][1] + rb2[nt], 0.0f));
        u32 p1 = bfpack(fmaxf(acc[nt][2] + rb2[nt], 0.0f),
                        fmaxf(acc[nt][3] + rb2[nt], 0.0f));
        sA[rb]       = (u16)p0;
        sA[rb + 136] = (u16)(p0 >> 16);
        sA[rb + 272] = (u16)p1;
        sA[rb + 408] = (u16)(p1 >> 16);
    }
    __syncthreads();
    if (!do_pool) {
        // coalesced row store: 16 rows x 16 uint4 chunks = 256 = 1/thread
        int rr = tid >> 4, c8 = (tid & 15) << 3;
        int nn = blockIdx.x * 16 + rr;
        *(uint4*)&x_out[(long)nn * H + c8] = *(const uint4*)&sA[rr * 136 + c8];
    } else {
        // pool epilogue v2: 64 threads x 2 cols (u32 reads), FULL unroll ->
        // all 16 LDS loads in flight (v1's unroll-4 exposed ~480cy latency)
        if (tid < 64) {
            int c2 = tid * 2;
            float s0 = 0.0f, s1 = 0.0f;
            int cur = sBt[0];
            #pragma unroll
            for (int rr = 0; rr < 16; rr++) {
                int bb = sBt[rr];
                if (bb != cur) {
                    atomicAdd(&sums[cur * H + c2],     s0);
                    atomicAdd(&sums[cur * H + c2 + 1], s1);
                    s0 = s1 = 0.0f; cur = bb;
                }
                u32 v = *(const u32*)&sA[rr * 136 + c2];
                s0 += bf2f(v & 0xffff);
                s1 += bf2f(v >> 16);
            }
            atomicAdd(&sums[cur * H + c2],     s0);
            atomicAdd(&sums[cur * H + c2 + 1], s1);
        } else if (tid == 64) {
            int cur = sBt[0];
            float cc = 0.0f;
            #pragma unroll
            for (int rr = 0; rr < 16; rr++) {
                int bb = sBt[rr];
                if (bb != cur) {
                    atomicAdd(&cnt[cur], cc);
                    cc = 0.0f; cur = bb;
                }
                cc += 1.0f;
            }
            atomicAdd(&cnt[cur], cc);
        }
    }
}

// ---------------- regressor ------------------------------------------------
__global__ __launch_bounds__(128) void regressor_kernel(
    const float* __restrict__ sums, const float* __restrict__ cnt,
    const float* __restrict__ depth,
    const float* __restrict__ w1, const float* __restrict__ b1,
    const float* __restrict__ w2, const float* __restrict__ b2,
    float* __restrict__ out)
{
    __shared__ float s_mean[H];
    __shared__ float s_red[2];
    int b = blockIdx.x;
    int j = threadIdx.x;
    float c = fmaxf(cnt[b], 1.0f);
    s_mean[j] = sums[b * H + j] / c;
    __syncthreads();
    float h = b1[j];
    #pragma unroll 8
    for (int k = 0; k < H; k++) h += s_mean[k] * w1[k * H + j];
    h += depth[b] * w1[H * H + j];
    h = fmaxf(h, 0.0f);
    float p = h * w2[j];
    #pragma unroll
    for (int off = 32; off >= 1; off >>= 1) p += __shfl_down(p, off, 64);
    if ((j & 63) == 0) s_red[j >> 6] = p;
    __syncthreads();
    if (j == 0) out[b] = s_red[0] + s_red[1] + b2[0];
}

extern "C" void kernel_launch(void* const* d_in, const int* in_sizes, int n_in,
                              void* d_out, int out_size, void* d_ws, size_t ws_size,
                              hipStream_t stream)
{
    const int*   ids   = (const int*)  d_in[0];
    const int*   eidx  = (const int*)  d_in[1];
    const float* eattr = (const float*)d_in[2];
    const int*   batch = (const int*)  d_in[3];
    const float* depth = (const float*)d_in[4];
    const float* id_w1 = (const float*)d_in[5];
    const float* id_b1 = (const float*)d_in[6];
    const float* id_w2 = (const float*)d_in[7];
    const float* id_b2 = (const float*)d_in[8];
    const float* ed_w1 = (const float*)d_in[9];
    const float* ed_b1 = (const float*)d_in[10];
    const float* ed_w2 = (const float*)d_in[11];
    const float* ed_b2 = (const float*)d_in[12];
    const float* c1_w1 = (const float*)d_in[13];
    const float* c1_b1 = (const float*)d_in[14];
    const float* c1_w2 = (const float*)d_in[15];
    const float* c1_b2 = (const float*)d_in[16];
    const float* c2_w1 = (const float*)d_in[17];
    const float* c2_b1 = (const float*)d_in[18];
    const float* c2_w2 = (const float*)d_in[19];
    const float* c2_b2 = (const float*)d_in[20];
    const float* rg_w1 = (const float*)d_in[21];
    const float* rg_b1 = (const float*)d_in[22];
    const float* rg_w2 = (const float*)d_in[23];
    const float* rg_b2 = (const float*)d_in[24];

    char* ws = (char*)d_ws;
    u16*   e_buf    = (u16*)  (ws);                      // 153,600,000 B (CSR order)
    u16*   x_buf    = (u16*)  (ws + 153600000);          //  25,600,000 B
    u16*   xs_buf   = (u16*)  (ws + 179200000);          //  25,600,000 B (x ping-pong)
    float* sums_buf = (float*)(ws + 204800000);          //     262,144 B
    float* cnt_buf  = (float*)(ws + 205062144);          //       2,048 B (contiguous after sums)
    int*   counts   = (int*)  (ws + 205064192);          //     401,408 B
    int*   chunk_sc = (int*)  (ws + 205465600);          //     401,408 B
    int*   bsum_raw = (int*)  (ws + 205867008);          //         512 B
    int*   src_list = (int*)  (ws + 205868032);          //   2,400,000 B
    short8* ed_w1p  = (short8*)(ws + 208268032);         //       8,192 B
    short8* ed_w2p  = (short8*)(ws + 208276224);         //      32,768 B
    short8* c1_w1p  = (short8*)(ws + 208308992);
    short8* c1_w2p  = (short8*)(ws + 208341760);
    short8* c2_w1p  = (short8*)(ws + 208374528);
    short8* c2_w2p  = (short8*)(ws + 208407296);
    short8* id_w2p  = (short8*)(ws + 208440064);
    int*   row_start = counts;    // counts dead after fill; reuse
    u16*   attr_perm = xs_buf;    // alias: attr_perm dead before gine1 write

    // zero counts (must precede hist)
    hipMemsetAsync(counts, 0, 401408, stream);

    // pack (0..49) + hist (50..2393) + zero sums/cnt (2394..2458)
    const int HIST_BLKS = (N_EDGES + 255) / 256;   // 2344
    pack_hist_kernel<<<50 + HIST_BLKS + 65, 256, 0, stream>>>(
        ed_w1, ed_w2, c1_w1, c1_w2, c2_w1, c2_w2, id_w2,
        ed_w1p, ed_w2p, c1_w1p, c1_w2p, c2_w1p, c2_w2p, id_w2p,
        eidx, counts, (uint4*)sums_buf);

    // scan1 (blocks 0..97) + node MLP (blocks 98..1660, one tile each)
    scan_node_kernel<<<N_CHUNKS + 1563, 256, 0, stream>>>(
        counts, chunk_sc, bsum_raw,
        ids, id_w1, id_b1, id_w2p, id_b2, x_buf);

    // fill (local bsum scan inside)
    fill_kernel<<<(N_EDGES + 255) / 256, 256, 0, stream>>>(
        eidx, chunk_sc, bsum_raw, counts, src_list, eattr, attr_perm);

    // edge MLP (+finalize row_start on blocks 0..391); 3125*3 = 9375 tiles exact
    edge_mlp_mfma<<<3125, 256, 0, stream>>>(
        attr_perm, chunk_sc, bsum_raw, row_start,
        ed_w1p, ed_b1, ed_w2p, ed_b2, e_buf);

    // layer 1 (fused aggregate + conv MLP): x_buf -> xs_buf
    gine_fused<<<6250, 256, 0, stream>>>(row_start, src_list, e_buf, x_buf,
                                         c1_w1p, c1_b1, c1_w2p, c1_b2, xs_buf,
                                         batch, sums_buf, cnt_buf, 0);
    // layer 2 (+fused mean-pool): xs_buf -> sums/cnt directly
    gine_fused<<<6250, 256, 0, stream>>>(row_start, src_list, e_buf, xs_buf,
                                         c2_w1p, c2_b1, c2_w2p, c2_b2, x_buf,
                                         batch, sums_buf, cnt_buf, 1);

    // regressor
    regressor_kernel<<<NB, 128, 0, stream>>>(sums_buf, cnt_buf, depth,
                                             rg_w1, rg_b1, rg_w2, rg_b2, (float*)d_out);
}

// Round 12
// 356.362 us; speedup vs baseline: 1.0125x; 1.0125x over previous
//
#include <hip/hip_runtime.h>
#include <hip/hip_bf16.h>

#define N_NODES 100000
#define N_EDGES 600000
#define NB      512
#define H       128
#define ED      8
#define SCAN_CHUNK 1024
#define N_CHUNKS   98   // 98*1024 = 100352 >= N_NODES+1

typedef __attribute__((ext_vector_type(8))) short short8;
typedef __attribute__((ext_vector_type(4))) float f32x4;
typedef __attribute__((ext_vector_type(4))) unsigned int u32x4;
typedef unsigned short u16;
typedef unsigned int   u32;

static __device__ __forceinline__ u16 f2bf(float f) {
    u32 u = __float_as_uint(f);
    u32 r = u + 0x7fffu + ((u >> 16) & 1u);
    return (u16)(r >> 16);
}
static __device__ __forceinline__ float bf2f(u32 h) {
    return __uint_as_float(h << 16);
}
// packed f32->bf16 (RNE, same as f2bf): lo->bits[15:0], hi->bits[31:16]
static __device__ __forceinline__ u32 bfpack(float lo, float hi) {
    u32 r;
    asm("v_cvt_pk_bf16_f32 %0, %1, %2" : "=v"(r) : "v"(lo), "v"(hi));
    return r;
}

// ---- fused: weight pack (0..49) + hist (50..2393) + zero sums (2394..2458)
__global__ __launch_bounds__(256) void pack_hist_kernel(
    const float* __restrict__ W0, const float* __restrict__ W1,
    const float* __restrict__ W2, const float* __restrict__ W3,
    const float* __restrict__ W4, const float* __restrict__ W5,
    const float* __restrict__ W6,
    short8* __restrict__ O0, short8* __restrict__ O1,
    short8* __restrict__ O2, short8* __restrict__ O3,
    short8* __restrict__ O4, short8* __restrict__ O5,
    short8* __restrict__ O6,
    const int* __restrict__ edge_index, int* __restrict__ counts,
    uint4* __restrict__ sums_zero)
{
    const int HIST_BLKS = (N_EDGES + 255) / 256;   // 2344
    if (blockIdx.x >= 50 + HIST_BLKS) {
        // zero sums_buf (fallback target): 262,144 B = 16384 uint4
        int idx = (blockIdx.x - 50 - HIST_BLKS) * 256 + threadIdx.x;
        if (idx < 16384) sums_zero[idx] = make_uint4(0, 0, 0, 0);
        return;
    }
    if (blockIdx.x >= 50) {
        int e = (blockIdx.x - 50) * 256 + threadIdx.x;
        if (e < N_EDGES) atomicAdd(&counts[edge_index[N_EDGES + e]], 1);
        return;
    }
    int gid = blockIdx.x * 256 + threadIdx.x;   // < 12800 exactly
    const float* W; short8* O; int Krows, kkmax, slot;
    if (gid < 512) { W = W0; O = O0; Krows = ED; kkmax = 1; slot = gid; }
    else {
        int m = (gid - 512) / 2048;
        slot = (gid - 512) % 2048;
        Krows = H; kkmax = 4;
        switch (m) {
            case 0: W = W1; O = O1; break;
            case 1: W = W2; O = O2; break;
            case 2: W = W3; O = O3; break;
            case 3: W = W4; O = O4; break;
            case 4: W = W5; O = O5; break;
            default: W = W6; O = O6; break;
        }
    }
    int lane = slot & 63;
    int t = slot >> 6;
    int nt = t & 1; t >>= 1;
    int kk = t % kkmax;
    int w  = t / kkmax;
    int quad = lane >> 4, n15 = lane & 15;
    int n = w * 32 + nt * 16 + n15;
    short8 v;
    #pragma unroll
    for (int j = 0; j < 8; j++) {
        int k = kk * 32 + quad * 8 + j;
        v[j] = (k < Krows) ? (short)f2bf(W[k * H + n]) : (short)0;
    }
    O[slot] = v;
}

// ---- fused: per-chunk scan (blocks 0..97) + node MLP (blocks 98..865) -----
__global__ __launch_bounds__(256) void scan_node_kernel(
    const int* __restrict__ counts, int* __restrict__ chunk_scan,
    int* __restrict__ bsum_raw,
    const int* __restrict__ ids,
    const float* __restrict__ w1, const float* __restrict__ b1,
    const short8* __restrict__ pW2, const float* __restrict__ b2,
    u16* __restrict__ x_out)
{
    __shared__ u16 sH[64 * 136];
    __shared__ float s_x0[64];
    __shared__ int sS[256];
    int tid = threadIdx.x;

    if (blockIdx.x < N_CHUNKS) {
        // ---- scan1: 1024-elem chunk, 4 elems/thread ----
        int base = blockIdx.x * SCAN_CHUNK + tid * 4;
        int4 v = *(const int4*)&counts[base];
        int q0 = v.x, q1 = q0 + v.y, q2 = q1 + v.z, q3 = q2 + v.w;
        sS[tid] = q3;
        __syncthreads();
        #pragma unroll
        for (int off = 1; off < 256; off <<= 1) {
            int t = (tid >= off) ? sS[tid - off] : 0;
            __syncthreads();
            sS[tid] += t;
            __syncthreads();
        }
        int excl = sS[tid] - q3;
        int4 o;
        o.x = excl; o.y = excl + q0; o.z = excl + q1; o.w = excl + q2;
        *(int4*)&chunk_scan[base] = o;
        if (tid == 255) bsum_raw[blockIdx.x] = sS[255];
        return;
    }

    // ---- node MLP on blocks 98..865 (768 blocks, 2-3 tiles each) ----
    int bid = blockIdx.x - N_CHUNKS;
    int w = tid >> 6, lane = tid & 63, quad = lane >> 4, n15 = lane & 15;
    short8 fW2[4][2];
    #pragma unroll
    for (int kk = 0; kk < 4; kk++) {
        fW2[kk][0] = pW2[((w * 4 + kk) * 2 + 0) * 64 + lane];
        fW2[kk][1] = pW2[((w * 4 + kk) * 2 + 1) * 64 + lane];
    }
    float rb2[2] = { b2[w * 32 + n15], b2[w * 32 + 16 + n15] };
    float w1c = w1[tid & 127], b1c = b1[tid & 127];
    const int ntile = (N_NODES + 63) / 64;   // 1563
    for (int tile = bid; tile < ntile; tile += 768) {
        int row0 = tile * 64;
        if (tid < 64) {
            int n = row0 + tid;
            float x0 = (n < N_NODES) ? (float)ids[n] / 281474976710655.0f : 0.0f;
            s_x0[tid] = fminf(fmaxf(x0, 0.0f), 1.0f);
        }
        __syncthreads();
        int half = tid >> 7, c = tid & 127;
        #pragma unroll
        for (int rr = 0; rr < 32; rr += 2) {
            int r = half + rr * 2;
            u32 p = bfpack(fmaxf(s_x0[r] * w1c + b1c, 0.0f),
                           fmaxf(s_x0[r + 2] * w1c + b1c, 0.0f));
            sH[r * 136 + c]       = (u16)p;
            sH[(r + 2) * 136 + c] = (u16)(p >> 16);
        }
        __syncthreads();
        f32x4 acc[4][2];
        #pragma unroll
        for (int s = 0; s < 4; s++) { acc[s][0] = (f32x4){0,0,0,0}; acc[s][1] = (f32x4){0,0,0,0}; }
        #pragma unroll
        for (int kk = 0; kk < 4; kk++) {
            #pragma unroll
            for (int s = 0; s < 4; s++) {
                short8 a = *(const short8*)&sH[(s * 16 + n15) * 136 + kk * 32 + quad * 8];
                acc[s][0] = __builtin_amdgcn_mfma_f32_16x16x32_bf16(a, fW2[kk][0], acc[s][0], 0, 0, 0);
                acc[s][1] = __builtin_amdgcn_mfma_f32_16x16x32_bf16(a, fW2[kk][1], acc[s][1], 0, 0, 0);
            }
        }
        __syncthreads();
        #pragma unroll
        for (int s = 0; s < 4; s++)
            #pragma unroll
            for (int nt = 0; nt < 2; nt++) {
                int col = w * 32 + nt * 16 + n15;
                int rb = (s * 16 + quad * 4) * 136 + col;
                u32 p0 = bfpack(acc[s][nt][0] + rb2[nt], acc[s][nt][1] + rb2[nt]);
                u32 p1 = bfpack(acc[s][nt][2] + rb2[nt], acc[s][nt][3] + rb2[nt]);
                sH[rb]       = (u16)p0;
                sH[rb + 136] = (u16)(p0 >> 16);
                sH[rb + 272] = (u16)p1;
                sH[rb + 408] = (u16)(p1 >> 16);
            }
        __syncthreads();
        for (int idx = tid; idx < 64 * 16; idx += 256) {
            int r = idx >> 4, c8 = (idx & 15) << 3;
            int n = row0 + r;
            if (n < N_NODES)
                *(uint4*)&x_out[(long)n * H + c8] = *(const uint4*)&sH[r * 136 + c8];
        }
        __syncthreads();
    }
}

// ---- fill (+local 98-chunk scan, replaces scan2 dispatch) -----------------
__global__ __launch_bounds__(256) void fill_kernel(
    const int* __restrict__ edge_index,
    const int* __restrict__ chunk_scan, const int* __restrict__ bsum_raw,
    int* __restrict__ counts, int* __restrict__ src_list,
    const float* __restrict__ attr, u16* __restrict__ attr_perm)
{
    __shared__ int sB[128];
    int tid = threadIdx.x;
    int v0 = 0;
    if (tid < 128) {
        v0 = (tid < N_CHUNKS) ? bsum_raw[tid] : 0;
        sB[tid] = v0;
    }
    __syncthreads();
    #pragma unroll
    for (int off = 1; off < 128; off <<= 1) {
        int t = (tid < 128 && tid >= off) ? sB[tid - off] : 0;
        __syncthreads();
        if (tid < 128) sB[tid] += t;
        __syncthreads();
    }
    if (tid < 128) sB[tid] -= v0;   // exclusive
    __syncthreads();

    int e = blockIdx.x * 256 + tid;
    if (e >= N_EDGES) return;
    int src = edge_index[e];
    int dst = edge_index[N_EDGES + e];
    int slot = atomicAdd(&counts[dst], -1) - 1;
    int pos = chunk_scan[dst] + sB[dst >> 10] + slot;
    src_list[pos] = src;
    float4 a0 = *(const float4*)&attr[(long)e * ED];
    float4 a1 = *(const float4*)&attr[(long)e * ED + 4];
    u32 w0 = bfpack(a0.x, a0.y);
    u32 w1 = bfpack(a0.z, a0.w);
    u32 w2 = bfpack(a1.x, a1.y);
    u32 w3 = bfpack(a1.z, a1.w);
    *(uint4*)&attr_perm[(long)pos * ED] = make_uint4(w0, w1, w2, w3);
}

// ---- edge MLP v3 (+finalize row_start prologue on blocks 0..391) ----------
__global__ __launch_bounds__(256) void edge_mlp_mfma(
    const u16* __restrict__ attr_perm,
    const int* __restrict__ chunk_scan, const int* __restrict__ bsum_raw,
    int* __restrict__ row_start,
    const short8* __restrict__ pW1, const float* __restrict__ b1,
    const short8* __restrict__ pW2, const float* __restrict__ b2,
    u16* __restrict__ e_perm)
{
    __shared__ u16 sH[64 * 136];
    __shared__ int sB[128];
    int tid = threadIdx.x;

    if (blockIdx.x < 392) {   // finalize: row_start[i] = chunk_scan[i]+bsum[i>>10]
        int v0 = 0;
        if (tid < 128) {
            v0 = (tid < N_CHUNKS) ? bsum_raw[tid] : 0;
            sB[tid] = v0;
        }
        __syncthreads();
        #pragma unroll
        for (int off = 1; off < 128; off <<= 1) {
            int t = (tid < 128 && tid >= off) ? sB[tid - off] : 0;
            __syncthreads();
            if (tid < 128) sB[tid] += t;
            __syncthreads();
        }
        if (tid < 128) sB[tid] -= v0;
        __syncthreads();
        int i = blockIdx.x * 256 + tid;   // 392*256 = 100352 >= N_NODES+1
        if (i <= N_NODES) row_start[i] = chunk_scan[i] + sB[i >> 10];
        __syncthreads();
    }

    int w = tid >> 6, lane = tid & 63, quad = lane >> 4, n15 = lane & 15;
    short8 fW1[2];
    fW1[0] = pW1[(w * 2 + 0) * 64 + lane];
    fW1[1] = pW1[(w * 2 + 1) * 64 + lane];
    short8 fW2[4][2];
    #pragma unroll
    for (int kk = 0; kk < 4; kk++) {
        fW2[kk][0] = pW2[((w * 4 + kk) * 2 + 0) * 64 + lane];
        fW2[kk][1] = pW2[((w * 4 + kk) * 2 + 1) * 64 + lane];
    }
    float rb1[2] = { b1[w * 32 + n15], b1[w * 32 + 16 + n15] };
    float rb2[2] = { b2[w * 32 + n15], b2[w * 32 + 16 + n15] };
    const short8 zero8 = (short8){0,0,0,0,0,0,0,0};
    const int ntile = N_EDGES / 64;   // 9375 exact = 3 * 3125
    for (int tile = blockIdx.x; tile < ntile; tile += gridDim.x) {
        int row0 = tile * 64;
        short8 av[4];
        #pragma unroll
        for (int s = 0; s < 4; s++) {
            av[s] = zero8;
            if (quad == 0)
                av[s] = *(const short8*)&attr_perm[(long)(row0 + s * 16 + n15) * ED];
        }
        // GEMM1 (K=32, one step)
        f32x4 acc[4][2];
        #pragma unroll
        for (int s = 0; s < 4; s++) { acc[s][0] = (f32x4){0,0,0,0}; acc[s][1] = (f32x4){0,0,0,0}; }
        #pragma unroll
        for (int s = 0; s < 4; s++) {
            acc[s][0] = __builtin_amdgcn_mfma_f32_16x16x32_bf16(av[s], fW1[0], acc[s][0], 0, 0, 0);
            acc[s][1] = __builtin_amdgcn_mfma_f32_16x16x32_bf16(av[s], fW1[1], acc[s][1], 0, 0, 0);
        }
        #pragma unroll
        for (int s = 0; s < 4; s++)
            #pragma unroll
            for (int nt = 0; nt < 2; nt++) {
                int col = w * 32 + nt * 16 + n15;
                int rb = (s * 16 + quad * 4) * 136 + col;
                u32 p0 = bfpack(fmaxf(acc[s][nt][0] + rb1[nt], 0.0f),
                                fmaxf(acc[s][nt][1] + rb1[nt], 0.0f));
                u32 p1 = bfpack(fmaxf(acc[s][nt][2] + rb1[nt], 0.0f),
                                fmaxf(acc[s][nt][3] + rb1[nt], 0.0f));
                sH[rb]       = (u16)p0;
                sH[rb + 136] = (u16)(p0 >> 16);
                sH[rb + 272] = (u16)p1;
                sH[rb + 408] = (u16)(p1 >> 16);
            }
        __syncthreads();
        // GEMM2 (K=128)
        #pragma unroll
        for (int s = 0; s < 4; s++) { acc[s][0] = (f32x4){0,0,0,0}; acc[s][1] = (f32x4){0,0,0,0}; }
        #pragma unroll
        for (int kk = 0; kk < 4; kk++) {
            #pragma unroll
            for (int s = 0; s < 4; s++) {
                short8 a = *(const short8*)&sH[(s * 16 + n15) * 136 + kk * 32 + quad * 8];
                acc[s][0] = __builtin_amdgcn_mfma_f32_16x16x32_bf16(a, fW2[kk][0], acc[s][0], 0, 0, 0);
                acc[s][1] = __builtin_amdgcn_mfma_f32_16x16x32_bf16(a, fW2[kk][1], acc[s][1], 0, 0, 0);
            }
        }
        __syncthreads();
        #pragma unroll
        for (int s = 0; s < 4; s++)
            #pragma unroll
            for (int nt = 0; nt < 2; nt++) {
                int col = w * 32 + nt * 16 + n15;
                int rb = (s * 16 + quad * 4) * 136 + col;
                u32 p0 = bfpack(acc[s][nt][0] + rb2[nt], acc[s][nt][1] + rb2[nt]);
                u32 p1 = bfpack(acc[s][nt][2] + rb2[nt], acc[s][nt][3] + rb2[nt]);
                sH[rb]       = (u16)p0;
                sH[rb + 136] = (u16)(p0 >> 16);
                sH[rb + 272] = (u16)p1;
                sH[rb + 408] = (u16)(p1 >> 16);
            }
        __syncthreads();
        for (int idx = tid; idx < 64 * 16; idx += 256) {
            int r = idx >> 4, c8 = (idx & 15) << 3;
            *(uint4*)&e_perm[(long)(row0 + r) * H + c8] = *(const uint4*)&sH[r * 136 + c8];
        }
        __syncthreads();
    }
}

// ---- fused GINE layer: barrier-free gather + 16-row conv (+opt. pool) -----
// do_pool=1: skip x_out store; write per-block SEGMENT PARTIALS (no atomics
// on hot path; >4-segment overflow falls back to atomicAdd into sums).
static __device__ __forceinline__ void acc8(float* a, u32x4 xv, u32x4 ev) {
    #pragma unroll
    for (int q = 0; q < 4; q++) {
        a[2 * q + 0] += fmaxf(bf2f(xv[q] & 0xffff) + bf2f(ev[q] & 0xffff), 0.0f);
        a[2 * q + 1] += fmaxf(bf2f(xv[q] >> 16)    + bf2f(ev[q] >> 16),    0.0f);
    }
}

__global__ __launch_bounds__(256) void gine_fused(
    const int* __restrict__ row_start,
    const int* __restrict__ src_list,
    const u16* __restrict__ e_perm,
    const u16* __restrict__ x,
    const short8* __restrict__ pW1, const float* __restrict__ b1,
    const short8* __restrict__ pW2, const float* __restrict__ b2,
    u16* __restrict__ x_out,
    const int* __restrict__ batch,
    float* __restrict__ sums,          // fallback only
    float* __restrict__ part_sums,     // [6250][4][H]
    int* __restrict__ part_id,         // [6250][4]
    int do_pool)
{
    __shared__ u16 sA[16 * 136];
    __shared__ int sBt[16];
    int tid  = threadIdx.x;
    int lane = tid & 63;
    int l16  = lane & 15;
    int base = lane & 48;            // group base lane within wave
    int fo   = l16 * 8;              // 8 u16 cols per lane
    int r    = tid >> 4;             // local row 0..15
    int n    = blockIdx.x * 16 + r;  // exact: 6250*16 = 100000
    const u16* xb = x + fo;

    if (do_pool && tid < 16) sBt[tid] = batch[blockIdx.x * 16 + tid];

    // ---------- gather phase (no barriers) ----------
    int beg = row_start[n];
    int end = row_start[n + 1];
    float a[8], b[8];
    #pragma unroll
    for (int q = 0; q < 8; q++) { a[q] = 0.0f; b[q] = 0.0f; }

    for (int j0 = beg; j0 < end; j0 += 16) {
        int m = min(16, end - j0);
        int sv = src_list[j0 + min(l16, m - 1)];
        const u16* ej = e_perm + (long)j0 * H + fo;
        int j = 0;
        for (; j + 2 <= m; j += 2) {
            int s0 = __shfl(sv, base | j);
            int s1 = __shfl(sv, base | (j + 1));
            u32x4 xv0 = *(const u32x4*)(xb + (long)s0 * H);
            u32x4 ev0 = *(const u32x4*)(ej + (long)(j + 0) * H);
            u32x4 xv1 = *(const u32x4*)(xb + (long)s1 * H);
            u32x4 ev1 = *(const u32x4*)(ej + (long)(j + 1) * H);
            acc8(a, xv0, ev0);
            acc8(b, xv1, ev1);
        }
        if (j < m) {
            int s0 = __shfl(sv, base | j);
            u32x4 xv0 = *(const u32x4*)(xb + (long)s0 * H);
            u32x4 ev0 = *(const u32x4*)(ej + (long)j * H);
            acc8(a, xv0, ev0);
        }
    }
    u32x4 xself = *(const u32x4*)(xb + (long)n * H);
    u32x4 xsrow;
    #pragma unroll
    for (int q = 0; q < 4; q++) {
        float o0 = bf2f(xself[q] & 0xffff) + a[2 * q + 0] + b[2 * q + 0];
        float o1 = bf2f(xself[q] >> 16)    + a[2 * q + 1] + b[2 * q + 1];
        xsrow[q] = bfpack(o0, o1);
    }
    *(uint4*)&sA[r * 136 + fo] = *(uint4*)&xsrow;   // xs row -> LDS (bf16)
    __syncthreads();

    // ---------- conv phase: 16x128 tile, 2 GEMMs ----------
    int w = tid >> 6, quad = lane >> 4, n15 = l16;
    float rb1[2] = { b1[w * 32 + n15], b1[w * 32 + 16 + n15] };
    float rb2[2] = { b2[w * 32 + n15], b2[w * 32 + 16 + n15] };
    // GEMM1 (weights streamed from global/L2 to keep VGPR low)
    f32x4 acc[2];
    acc[0] = (f32x4){0,0,0,0}; acc[1] = (f32x4){0,0,0,0};
    #pragma unroll
    for (int kk = 0; kk < 4; kk++) {
        short8 av = *(const short8*)&sA[n15 * 136 + kk * 32 + quad * 8];
        short8 w0 = pW1[((w * 4 + kk) * 2 + 0) * 64 + lane];
        short8 w1v = pW1[((w * 4 + kk) * 2 + 1) * 64 + lane];
        acc[0] = __builtin_amdgcn_mfma_f32_16x16x32_bf16(av, w0, acc[0], 0, 0, 0);
        acc[1] = __builtin_amdgcn_mfma_f32_16x16x32_bf16(av, w1v, acc[1], 0, 0, 0);
    }
    __syncthreads();   // sA reads done
    #pragma unroll
    for (int nt = 0; nt < 2; nt++) {
        int col = w * 32 + nt * 16 + n15;
        int rb = (quad * 4) * 136 + col;
        u32 p0 = bfpack(fmaxf(acc[nt][0] + rb1[nt], 0.0f),
                        fmaxf(acc[nt][1] + rb1[nt], 0.0f));
        u32 p1 = bfpack(fmaxf(acc[nt][2] + rb1[nt], 0.0f),
                        fmaxf(acc[nt][3] + rb1[nt], 0.0f));
        sA[rb]       = (u16)p0;
        sA[rb + 136] = (u16)(p0 >> 16);
        sA[rb + 272] = (u16)p1;
        sA[rb + 408] = (u16)(p1 >> 16);
    }
    __syncthreads();
    // GEMM2
    acc[0] = (f32x4){0,0,0,0}; acc[1] = (f32x4){0,0,0,0};
    #pragma unroll
    for (int kk = 0; kk < 4; kk++) {
        short8 av = *(const short8*)&sA[n15 * 136 + kk * 32 + quad * 8];
        short8 w0 = pW2[((w * 4 + kk) * 2 + 0) * 64 + lane];
        short8 w1v = pW2[((w * 4 + kk) * 2 + 1) * 64 + lane];
        acc[0] = __builtin_amdgcn_mfma_f32_16x16x32_bf16(av, w0, acc[0], 0, 0, 0);
        acc[1] = __builtin_amdgcn_mfma_f32_16x16x32_bf16(av, w1v, acc[1], 0, 0, 0);
    }
    __syncthreads();   // sA reads done
    #pragma unroll
    for (int nt = 0; nt < 2; nt++) {
        int col = w * 32 + nt * 16 + n15;
        int rb = (quad * 4) * 136 + col;
        u32 p0 = bfpack(fmaxf(acc[nt][0] + rb2[nt], 0.0f),
                        fmaxf(acc[nt][1] + rb2[nt], 0.0f));
        u32 p1 = bfpack(fmaxf(acc[nt][2] + rb2[nt], 0.0f),
                        fmaxf(acc[nt][3] + rb2[nt], 0.0f));
        sA[rb]       = (u16)p0;
        sA[rb + 136] = (u16)(p0 >> 16);
        sA[rb + 272] = (u16)p1;
        sA[rb + 408] = (u16)(p1 >> 16);
    }
    __syncthreads();
    if (!do_pool) {
        // coalesced row store: 16 rows x 16 uint4 chunks = 256 = 1/thread
        int rr = tid >> 4, c8 = (tid & 15) << 3;
        int nn = blockIdx.x * 16 + rr;
        *(uint4*)&x_out[(long)nn * H + c8] = *(const uint4*)&sA[rr * 136 + c8];
    } else {
        // pool epilogue v3: per-block segment partials (no hot-path atomics)
        if (tid < 64) {
            int c2 = tid * 2;
            float s0 = 0.0f, s1 = 0.0f;
            int cur = sBt[0];
            int seg = 0;
            #pragma unroll
            for (int rr = 0; rr < 16; rr++) {
                int bb = sBt[rr];
                if (bb != cur) {
                    if (seg < 4) {
                        long pb = ((long)blockIdx.x * 4 + seg) * H;
                        part_sums[pb + c2]     = s0;
                        part_sums[pb + c2 + 1] = s1;
                    } else {   // overflow (never for this data): fallback
                        atomicAdd(&sums[cur * H + c2],     s0);
                        atomicAdd(&sums[cur * H + c2 + 1], s1);
                    }
                    s0 = s1 = 0.0f; cur = bb; seg++;
                }
                u32 v = *(const u32*)&sA[rr * 136 + c2];
                s0 += bf2f(v & 0xffff);
                s1 += bf2f(v >> 16);
            }
            if (seg < 4) {
                long pb = ((long)blockIdx.x * 4 + seg) * H;
                part_sums[pb + c2]     = s0;
                part_sums[pb + c2 + 1] = s1;
            } else {
                atomicAdd(&sums[cur * H + c2],     s0);
                atomicAdd(&sums[cur * H + c2 + 1], s1);
            }
        } else if (tid == 64) {
            int cur = sBt[0];
            int seg = 0;
            #pragma unroll
            for (int rr = 0; rr < 16; rr++) {
                int bb = sBt[rr];
                if (bb != cur) {
                    if (seg < 4) part_id[blockIdx.x * 4 + seg] = cur;
                    cur = bb; seg++;
                }
            }
            if (seg < 4) part_id[blockIdx.x * 4 + seg] = cur;
            for (int s2 = seg + 1; s2 < 4; s2++) part_id[blockIdx.x * 4 + s2] = -1;
        }
    }
}

// ---- regressor: binary-search node range; reduce segment partials --------
__global__ __launch_bounds__(128) void regressor_kernel(
    const float* __restrict__ sums,          // fallback contributions
    const float* __restrict__ part_sums,
    const int* __restrict__ part_id,
    const int* __restrict__ batch,
    const float* __restrict__ depth,
    const float* __restrict__ w1, const float* __restrict__ b1,
    const float* __restrict__ w2, const float* __restrict__ b2,
    float* __restrict__ out)
{
    __shared__ float s_mean[H];
    __shared__ float s_red[2];
    int b = blockIdx.x;
    int j = threadIdx.x;
    // lower_bound(batch, b) and lower_bound(batch, b+1)
    int lo = 0, hi = N_NODES;
    while (lo < hi) { int mid = (lo + hi) >> 1; if (batch[mid] < b) lo = mid + 1; else hi = mid; }
    int n_start = lo;
    hi = N_NODES;
    while (lo < hi) { int mid = (lo + hi) >> 1; if (batch[mid] < b + 1) lo = mid + 1; else hi = mid; }
    int n_end = lo;
    float acc = sums[b * H + j];
    if (n_end > n_start) {
        int blk0 = n_start >> 4, blk1 = (n_end - 1) >> 4;
        for (int blk = blk0; blk <= blk1; blk++) {
            #pragma unroll
            for (int s = 0; s < 4; s++)
                if (part_id[blk * 4 + s] == b)
                    acc += part_sums[((long)blk * 4 + s) * H + j];
        }
    }
    float c = fmaxf((float)(n_end - n_start), 1.0f);
    s_mean[j] = acc / c;
    __syncthreads();
    float h = b1[j];
    #pragma unroll 8
    for (int k = 0; k < H; k++) h += s_mean[k] * w1[k * H + j];
    h += depth[b] * w1[H * H + j];
    h = fmaxf(h, 0.0f);
    float p = h * w2[j];
    #pragma unroll
    for (int off = 32; off >= 1; off >>= 1) p += __shfl_down(p, off, 64);
    if ((j & 63) == 0) s_red[j >> 6] = p;
    __syncthreads();
    if (j == 0) out[b] = s_red[0] + s_red[1] + b2[0];
}

extern "C" void kernel_launch(void* const* d_in, const int* in_sizes, int n_in,
                              void* d_out, int out_size, void* d_ws, size_t ws_size,
                              hipStream_t stream)
{
    const int*   ids   = (const int*)  d_in[0];
    const int*   eidx  = (const int*)  d_in[1];
    const float* eattr = (const float*)d_in[2];
    const int*   batch = (const int*)  d_in[3];
    const float* depth = (const float*)d_in[4];
    const float* id_w1 = (const float*)d_in[5];
    const float* id_b1 = (const float*)d_in[6];
    const float* id_w2 = (const float*)d_in[7];
    const float* id_b2 = (const float*)d_in[8];
    const float* ed_w1 = (const float*)d_in[9];
    const float* ed_b1 = (const float*)d_in[10];
    const float* ed_w2 = (const float*)d_in[11];
    const float* ed_b2 = (const float*)d_in[12];
    const float* c1_w1 = (const float*)d_in[13];
    const float* c1_b1 = (const float*)d_in[14];
    const float* c1_w2 = (const float*)d_in[15];
    const float* c1_b2 = (const float*)d_in[16];
    const float* c2_w1 = (const float*)d_in[17];
    const float* c2_b1 = (const float*)d_in[18];
    const float* c2_w2 = (const float*)d_in[19];
    const float* c2_b2 = (const float*)d_in[20];
    const float* rg_w1 = (const float*)d_in[21];
    const float* rg_b1 = (const float*)d_in[22];
    const float* rg_w2 = (const float*)d_in[23];
    const float* rg_b2 = (const float*)d_in[24];

    char* ws = (char*)d_ws;
    u16*   e_buf    = (u16*)  (ws);                      // 153,600,000 B (CSR order)
    u16*   x_buf    = (u16*)  (ws + 153600000);          //  25,600,000 B
    u16*   xs_buf   = (u16*)  (ws + 179200000);          //  25,600,000 B (x ping-pong)
    float* sums_buf = (float*)(ws + 204800000);          //     262,144 B (fallback)
    int*   counts   = (int*)  (ws + 205064192);          //     401,408 B
    int*   chunk_sc = (int*)  (ws + 205465600);          //     401,408 B
    int*   bsum_raw = (int*)  (ws + 205867008);          //         512 B
    int*   src_list = (int*)  (ws + 205868032);          //   2,400,000 B
    short8* ed_w1p  = (short8*)(ws + 208268032);         //       8,192 B
    short8* ed_w2p  = (short8*)(ws + 208276224);         //      32,768 B
    short8* c1_w1p  = (short8*)(ws + 208308992);
    short8* c1_w2p  = (short8*)(ws + 208341760);
    short8* c2_w1p  = (short8*)(ws + 208374528);
    short8* c2_w2p  = (short8*)(ws + 208407296);
    short8* id_w2p  = (short8*)(ws + 208440064);
    int*   row_start = counts;            // counts dead after fill; reuse
    u16*   attr_perm = xs_buf;            // dead before gine1 write
    float* part_sums = (float*)x_buf;     // x_buf dead after gine1 (12.8 MB < 25.6)
    int*   part_id   = chunk_sc;          // chunk_sc dead after edge_mlp (100 KB < 401)

    // zero counts (must precede hist)
    hipMemsetAsync(counts, 0, 401408, stream);

    // pack (0..49) + hist (50..2393) + zero sums (2394..2457)
    const int HIST_BLKS = (N_EDGES + 255) / 256;   // 2344
    pack_hist_kernel<<<50 + HIST_BLKS + 64, 256, 0, stream>>>(
        ed_w1, ed_w2, c1_w1, c1_w2, c2_w1, c2_w2, id_w2,
        ed_w1p, ed_w2p, c1_w1p, c1_w2p, c2_w1p, c2_w2p, id_w2p,
        eidx, counts, (uint4*)sums_buf);

    // scan1 (blocks 0..97) + node MLP (blocks 98..865)
    scan_node_kernel<<<N_CHUNKS + 768, 256, 0, stream>>>(
        counts, chunk_sc, bsum_raw,
        ids, id_w1, id_b1, id_w2p, id_b2, x_buf);

    // fill (local bsum scan inside)
    fill_kernel<<<(N_EDGES + 255) / 256, 256, 0, stream>>>(
        eidx, chunk_sc, bsum_raw, counts, src_list, eattr, attr_perm);

    // edge MLP (+finalize row_start on blocks 0..391); 3125*3 = 9375 tiles exact
    edge_mlp_mfma<<<3125, 256, 0, stream>>>(
        attr_perm, chunk_sc, bsum_raw, row_start,
        ed_w1p, ed_b1, ed_w2p, ed_b2, e_buf);

    // layer 1 (fused aggregate + conv MLP): x_buf -> xs_buf
    gine_fused<<<6250, 256, 0, stream>>>(row_start, src_list, e_buf, x_buf,
                                         c1_w1p, c1_b1, c1_w2p, c1_b2, xs_buf,
                                         batch, sums_buf, part_sums, part_id, 0);
    // layer 2 (+pool partials): xs_buf -> part_sums/part_id
    gine_fused<<<6250, 256, 0, stream>>>(row_start, src_list, e_buf, xs_buf,
                                         c2_w1p, c2_b1, c2_w2p, c2_b2, x_buf,
                                         batch, sums_buf, part_sums, part_id, 1);

    // regressor (reduces partials; counts via binary search over sorted batch)
    regressor_kernel<<<NB, 128, 0, stream>>>(sums_buf, part_sums, part_id, batch,
                                             depth, rg_w1, rg_b1, rg_w2, rg_b2,
                                             (float*)d_out);
}

// Round 13
// 353.994 us; speedup vs baseline: 1.0193x; 1.0067x over previous
//
#include <hip/hip_runtime.h>
#include <hip/hip_bf16.h>

#define N_NODES 100000
#define N_EDGES 600000
#define NB      512
#define H       128
#define ED      8
#define SCAN_CHUNK 1024
#define N_CHUNKS   98   // 98*1024 = 100352 >= N_NODES+1
#define EDGE_BLKS  3125
#define NODE_TILES 1563 // ceil(100000/64)

typedef __attribute__((ext_vector_type(8))) short short8;
typedef __attribute__((ext_vector_type(4))) float f32x4;
typedef __attribute__((ext_vector_type(4))) unsigned int u32x4;
typedef unsigned short u16;
typedef unsigned int   u32;

static __device__ __forceinline__ u16 f2bf(float f) {
    u32 u = __float_as_uint(f);
    u32 r = u + 0x7fffu + ((u >> 16) & 1u);
    return (u16)(r >> 16);
}
static __device__ __forceinline__ float bf2f(u32 h) {
    return __uint_as_float(h << 16);
}
// packed f32->bf16 (RNE, same as f2bf): lo->bits[15:0], hi->bits[31:16]
static __device__ __forceinline__ u32 bfpack(float lo, float hi) {
    u32 r;
    asm("v_cvt_pk_bf16_f32 %0, %1, %2" : "=v"(r) : "v"(lo), "v"(hi));
    return r;
}

// ---- fused: weight pack (0..49) + hist (50..2393) + zero sums (2394..2457)
__global__ __launch_bounds__(256) void pack_hist_kernel(
    const float* __restrict__ W0, const float* __restrict__ W1,
    const float* __restrict__ W2, const float* __restrict__ W3,
    const float* __restrict__ W4, const float* __restrict__ W5,
    const float* __restrict__ W6,
    short8* __restrict__ O0, short8* __restrict__ O1,
    short8* __restrict__ O2, short8* __restrict__ O3,
    short8* __restrict__ O4, short8* __restrict__ O5,
    short8* __restrict__ O6,
    const int* __restrict__ edge_index, int* __restrict__ counts,
    uint4* __restrict__ sums_zero)
{
    const int HIST_BLKS = (N_EDGES + 255) / 256;   // 2344
    if (blockIdx.x >= 50 + HIST_BLKS) {
        int idx = (blockIdx.x - 50 - HIST_BLKS) * 256 + threadIdx.x;
        if (idx < 16384) sums_zero[idx] = make_uint4(0, 0, 0, 0);
        return;
    }
    if (blockIdx.x >= 50) {
        int e = (blockIdx.x - 50) * 256 + threadIdx.x;
        if (e < N_EDGES) atomicAdd(&counts[edge_index[N_EDGES + e]], 1);
        return;
    }
    int gid = blockIdx.x * 256 + threadIdx.x;   // < 12800 exactly
    const float* W; short8* O; int Krows, kkmax, slot;
    if (gid < 512) { W = W0; O = O0; Krows = ED; kkmax = 1; slot = gid; }
    else {
        int m = (gid - 512) / 2048;
        slot = (gid - 512) % 2048;
        Krows = H; kkmax = 4;
        switch (m) {
            case 0: W = W1; O = O1; break;
            case 1: W = W2; O = O2; break;
            case 2: W = W3; O = O3; break;
            case 3: W = W4; O = O4; break;
            case 4: W = W5; O = O5; break;
            default: W = W6; O = O6; break;
        }
    }
    int lane = slot & 63;
    int t = slot >> 6;
    int nt = t & 1; t >>= 1;
    int kk = t % kkmax;
    int w  = t / kkmax;
    int quad = lane >> 4, n15 = lane & 15;
    int n = w * 32 + nt * 16 + n15;
    short8 v;
    #pragma unroll
    for (int j = 0; j < 8; j++) {
        int k = kk * 32 + quad * 8 + j;
        v[j] = (k < Krows) ? (short)f2bf(W[k * H + n]) : (short)0;
    }
    O[slot] = v;
}

// ---- scan1 only: 98 blocks, 1024-elem chunk, 4 elems/thread ---------------
__global__ __launch_bounds__(256) void scan_kernel(
    const int* __restrict__ counts, int* __restrict__ chunk_scan,
    int* __restrict__ bsum_raw)
{
    __shared__ int sS[256];
    int tid = threadIdx.x;
    int base = blockIdx.x * SCAN_CHUNK + tid * 4;
    int4 v = *(const int4*)&counts[base];
    int q0 = v.x, q1 = q0 + v.y, q2 = q1 + v.z, q3 = q2 + v.w;
    sS[tid] = q3;
    __syncthreads();
    #pragma unroll
    for (int off = 1; off < 256; off <<= 1) {
        int t = (tid >= off) ? sS[tid - off] : 0;
        __syncthreads();
        sS[tid] += t;
        __syncthreads();
    }
    int excl = sS[tid] - q3;
    int4 o;
    o.x = excl; o.y = excl + q0; o.z = excl + q1; o.w = excl + q2;
    *(int4*)&chunk_scan[base] = o;
    if (tid == 255) bsum_raw[blockIdx.x] = sS[255];
}

// ---- fill (+local 98-chunk scan, replaces scan2 dispatch) -----------------
__global__ __launch_bounds__(256) void fill_kernel(
    const int* __restrict__ edge_index,
    const int* __restrict__ chunk_scan, const int* __restrict__ bsum_raw,
    int* __restrict__ counts, int* __restrict__ src_list,
    const float* __restrict__ attr, u16* __restrict__ attr_perm)
{
    __shared__ int sB[128];
    int tid = threadIdx.x;
    int v0 = 0;
    if (tid < 128) {
        v0 = (tid < N_CHUNKS) ? bsum_raw[tid] : 0;
        sB[tid] = v0;
    }
    __syncthreads();
    #pragma unroll
    for (int off = 1; off < 128; off <<= 1) {
        int t = (tid < 128 && tid >= off) ? sB[tid - off] : 0;
        __syncthreads();
        if (tid < 128) sB[tid] += t;
        __syncthreads();
    }
    if (tid < 128) sB[tid] -= v0;   // exclusive
    __syncthreads();

    int e = blockIdx.x * 256 + tid;
    if (e >= N_EDGES) return;
    int src = edge_index[e];
    int dst = edge_index[N_EDGES + e];
    int slot = atomicAdd(&counts[dst], -1) - 1;
    int pos = chunk_scan[dst] + sB[dst >> 10] + slot;
    src_list[pos] = src;
    float4 a0 = *(const float4*)&attr[(long)e * ED];
    float4 a1 = *(const float4*)&attr[(long)e * ED + 4];
    u32 w0 = bfpack(a0.x, a0.y);
    u32 w1 = bfpack(a0.z, a0.w);
    u32 w2 = bfpack(a1.x, a1.y);
    u32 w3 = bfpack(a1.z, a1.w);
    *(uint4*)&attr_perm[(long)pos * ED] = make_uint4(w0, w1, w2, w3);
}

// ---- edge MLP + node MLP in one launch ------------------------------------
// blocks [0,3125): edge tiles (finalize row_start prologue on blocks 0..391)
// blocks [3125,4688): node MLP, one 64-row tile each
__global__ __launch_bounds__(256) void edge_node_mfma(
    const u16* __restrict__ attr_perm,
    const int* __restrict__ chunk_scan, const int* __restrict__ bsum_raw,
    int* __restrict__ row_start,
    const short8* __restrict__ pW1, const float* __restrict__ b1,
    const short8* __restrict__ pW2, const float* __restrict__ b2,
    u16* __restrict__ e_perm,
    const int* __restrict__ ids,
    const float* __restrict__ id_w1, const float* __restrict__ id_b1,
    const short8* __restrict__ id_pW2, const float* __restrict__ id_b2,
    u16* __restrict__ x_out)
{
    __shared__ u16 sH[64 * 136];
    __shared__ int sB[128];
    __shared__ float s_x0[64];
    int tid = threadIdx.x;

    if (blockIdx.x >= EDGE_BLKS) {
        // ---- node MLP: one 64-row tile ----
        int tile = blockIdx.x - EDGE_BLKS;   // < 1563
        int w = tid >> 6, lane = tid & 63, quad = lane >> 4, n15 = lane & 15;
        short8 fW2[4][2];
        #pragma unroll
        for (int kk = 0; kk < 4; kk++) {
            fW2[kk][0] = id_pW2[((w * 4 + kk) * 2 + 0) * 64 + lane];
            fW2[kk][1] = id_pW2[((w * 4 + kk) * 2 + 1) * 64 + lane];
        }
        float rb2[2] = { id_b2[w * 32 + n15], id_b2[w * 32 + 16 + n15] };
        float w1c = id_w1[tid & 127], b1c = id_b1[tid & 127];
        int row0 = tile * 64;
        if (tid < 64) {
            int n = row0 + tid;
            float x0 = (n < N_NODES) ? (float)ids[n] / 281474976710655.0f : 0.0f;
            s_x0[tid] = fminf(fmaxf(x0, 0.0f), 1.0f);
        }
        __syncthreads();
        int half = tid >> 7, c = tid & 127;
        #pragma unroll
        for (int rr = 0; rr < 32; rr += 2) {
            int r = half + rr * 2;
            u32 p = bfpack(fmaxf(s_x0[r] * w1c + b1c, 0.0f),
                           fmaxf(s_x0[r + 2] * w1c + b1c, 0.0f));
            sH[r * 136 + c]       = (u16)p;
            sH[(r + 2) * 136 + c] = (u16)(p >> 16);
        }
        __syncthreads();
        f32x4 acc[4][2];
        #pragma unroll
        for (int s = 0; s < 4; s++) { acc[s][0] = (f32x4){0,0,0,0}; acc[s][1] = (f32x4){0,0,0,0}; }
        #pragma unroll
        for (int kk = 0; kk < 4; kk++) {
            #pragma unroll
            for (int s = 0; s < 4; s++) {
                short8 a = *(const short8*)&sH[(s * 16 + n15) * 136 + kk * 32 + quad * 8];
                acc[s][0] = __builtin_amdgcn_mfma_f32_16x16x32_bf16(a, fW2[kk][0], acc[s][0], 0, 0, 0);
                acc[s][1] = __builtin_amdgcn_mfma_f32_16x16x32_bf16(a, fW2[kk][1], acc[s][1], 0, 0, 0);
            }
        }
        __syncthreads();
        #pragma unroll
        for (int s = 0; s < 4; s++)
            #pragma unroll
            for (int nt = 0; nt < 2; nt++) {
                int col = w * 32 + nt * 16 + n15;
                int rb = (s * 16 + quad * 4) * 136 + col;
                u32 p0 = bfpack(acc[s][nt][0] + rb2[nt], acc[s][nt][1] + rb2[nt]);
                u32 p1 = bfpack(acc[s][nt][2] + rb2[nt], acc[s][nt][3] + rb2[nt]);
                sH[rb]       = (u16)p0;
                sH[rb + 136] = (u16)(p0 >> 16);
                sH[rb + 272] = (u16)p1;
                sH[rb + 408] = (u16)(p1 >> 16);
            }
        __syncthreads();
        for (int idx = tid; idx < 64 * 16; idx += 256) {
            int r = idx >> 4, c8 = (idx & 15) << 3;
            int n = row0 + r;
            if (n < N_NODES)
                *(uint4*)&x_out[(long)n * H + c8] = *(const uint4*)&sH[r * 136 + c8];
        }
        return;
    }

    // ---- edge path ----
    if (blockIdx.x < 392) {   // finalize: row_start[i] = chunk_scan[i]+bsum[i>>10]
        int v0 = 0;
        if (tid < 128) {
            v0 = (tid < N_CHUNKS) ? bsum_raw[tid] : 0;
            sB[tid] = v0;
        }
        __syncthreads();
        #pragma unroll
        for (int off = 1; off < 128; off <<= 1) {
            int t = (tid < 128 && tid >= off) ? sB[tid - off] : 0;
            __syncthreads();
            if (tid < 128) sB[tid] += t;
            __syncthreads();
        }
        if (tid < 128) sB[tid] -= v0;
        __syncthreads();
        int i = blockIdx.x * 256 + tid;   // 392*256 = 100352 >= N_NODES+1
        if (i <= N_NODES) row_start[i] = chunk_scan[i] + sB[i >> 10];
        __syncthreads();
    }

    int w = tid >> 6, lane = tid & 63, quad = lane >> 4, n15 = lane & 15;
    short8 fW1[2];
    fW1[0] = pW1[(w * 2 + 0) * 64 + lane];
    fW1[1] = pW1[(w * 2 + 1) * 64 + lane];
    short8 fW2[4][2];
    #pragma unroll
    for (int kk = 0; kk < 4; kk++) {
        fW2[kk][0] = pW2[((w * 4 + kk) * 2 + 0) * 64 + lane];
        fW2[kk][1] = pW2[((w * 4 + kk) * 2 + 1) * 64 + lane];
    }
    float rb1[2] = { b1[w * 32 + n15], b1[w * 32 + 16 + n15] };
    float rb2[2] = { b2[w * 32 + n15], b2[w * 32 + 16 + n15] };
    const short8 zero8 = (short8){0,0,0,0,0,0,0,0};
    const int ntile = N_EDGES / 64;   // 9375 exact = 3 * 3125
    for (int tile = blockIdx.x; tile < ntile; tile += EDGE_BLKS) {
        int row0 = tile * 64;
        short8 av[4];
        #pragma unroll
        for (int s = 0; s < 4; s++) {
            av[s] = zero8;
            if (quad == 0)
                av[s] = *(const short8*)&attr_perm[(long)(row0 + s * 16 + n15) * ED];
        }
        // GEMM1 (K=32, one step)
        f32x4 acc[4][2];
        #pragma unroll
        for (int s = 0; s < 4; s++) { acc[s][0] = (f32x4){0,0,0,0}; acc[s][1] = (f32x4){0,0,0,0}; }
        #pragma unroll
        for (int s = 0; s < 4; s++) {
            acc[s][0] = __builtin_amdgcn_mfma_f32_16x16x32_bf16(av[s], fW1[0], acc[s][0], 0, 0, 0);
            acc[s][1] = __builtin_amdgcn_mfma_f32_16x16x32_bf16(av[s], fW1[1], acc[s][1], 0, 0, 0);
        }
        #pragma unroll
        for (int s = 0; s < 4; s++)
            #pragma unroll
            for (int nt = 0; nt < 2; nt++) {
                int col = w * 32 + nt * 16 + n15;
                int rb = (s * 16 + quad * 4) * 136 + col;
                u32 p0 = bfpack(fmaxf(acc[s][nt][0] + rb1[nt], 0.0f),
                                fmaxf(acc[s][nt][1] + rb1[nt], 0.0f));
                u32 p1 = bfpack(fmaxf(acc[s][nt][2] + rb1[nt], 0.0f),
                                fmaxf(acc[s][nt][3] + rb1[nt], 0.0f));
                sH[rb]       = (u16)p0;
                sH[rb + 136] = (u16)(p0 >> 16);
                sH[rb + 272] = (u16)p1;
                sH[rb + 408] = (u16)(p1 >> 16);
            }
        __syncthreads();
        // GEMM2 (K=128)
        #pragma unroll
        for (int s = 0; s < 4; s++) { acc[s][0] = (f32x4){0,0,0,0}; acc[s][1] = (f32x4){0,0,0,0}; }
        #pragma unroll
        for (int kk = 0; kk < 4; kk++) {
            #pragma unroll
            for (int s = 0; s < 4; s++) {
                short8 a = *(const short8*)&sH[(s * 16 + n15) * 136 + kk * 32 + quad * 8];
                acc[s][0] = __builtin_amdgcn_mfma_f32_16x16x32_bf16(a, fW2[kk][0], acc[s][0], 0, 0, 0);
                acc[s][1] = __builtin_amdgcn_mfma_f32_16x16x32_bf16(a, fW2[kk][1], acc[s][1], 0, 0, 0);
            }
        }
        __syncthreads();
        #pragma unroll
        for (int s = 0; s < 4; s++)
            #pragma unroll
            for (int nt = 0; nt < 2; nt++) {
                int col = w * 32 + nt * 16 + n15;
                int rb = (s * 16 + quad * 4) * 136 + col;
                u32 p0 = bfpack(acc[s][nt][0] + rb2[nt], acc[s][nt][1] + rb2[nt]);
                u32 p1 = bfpack(acc[s][nt][2] + rb2[nt], acc[s][nt][3] + rb2[nt]);
                sH[rb]       = (u16)p0;
                sH[rb + 136] = (u16)(p0 >> 16);
                sH[rb + 272] = (u16)p1;
                sH[rb + 408] = (u16)(p1 >> 16);
            }
        __syncthreads();
        for (int idx = tid; idx < 64 * 16; idx += 256) {
            int r = idx >> 4, c8 = (idx & 15) << 3;
            *(uint4*)&e_perm[(long)(row0 + r) * H + c8] = *(const uint4*)&sH[r * 136 + c8];
        }
        __syncthreads();
    }
}

// ---- fused GINE layer: barrier-free gather + 16-row conv (+opt. pool) -----
static __device__ __forceinline__ void acc8(float* a, u32x4 xv, u32x4 ev) {
    #pragma unroll
    for (int q = 0; q < 4; q++) {
        a[2 * q + 0] += fmaxf(bf2f(xv[q] & 0xffff) + bf2f(ev[q] & 0xffff), 0.0f);
        a[2 * q + 1] += fmaxf(bf2f(xv[q] >> 16)    + bf2f(ev[q] >> 16),    0.0f);
    }
}

__global__ __launch_bounds__(256) void gine_fused(
    const int* __restrict__ row_start,
    const int* __restrict__ src_list,
    const u16* __restrict__ e_perm,
    const u16* __restrict__ x,
    const short8* __restrict__ pW1, const float* __restrict__ b1,
    const short8* __restrict__ pW2, const float* __restrict__ b2,
    u16* __restrict__ x_out,
    const int* __restrict__ batch,
    float* __restrict__ sums,          // fallback only
    float* __restrict__ part_sums,     // [6250][4][H]
    int* __restrict__ part_id,         // [6250][4]
    int do_pool)
{
    __shared__ u16 sA[16 * 136];
    __shared__ int sBt[16];
    int tid  = threadIdx.x;
    int lane = tid & 63;
    int l16  = lane & 15;
    int base = lane & 48;            // group base lane within wave
    int fo   = l16 * 8;              // 8 u16 cols per lane
    int r    = tid >> 4;             // local row 0..15
    int n    = blockIdx.x * 16 + r;  // exact: 6250*16 = 100000
    const u16* xb = x + fo;

    if (do_pool && tid < 16) sBt[tid] = batch[blockIdx.x * 16 + tid];

    // ---------- gather phase (no barriers) ----------
    int beg = row_start[n];
    int end = row_start[n + 1];
    float a[8], b[8];
    #pragma unroll
    for (int q = 0; q < 8; q++) { a[q] = 0.0f; b[q] = 0.0f; }

    for (int j0 = beg; j0 < end; j0 += 16) {
        int m = min(16, end - j0);
        int sv = src_list[j0 + min(l16, m - 1)];
        const u16* ej = e_perm + (long)j0 * H + fo;
        int j = 0;
        for (; j + 2 <= m; j += 2) {
            int s0 = __shfl(sv, base | j);
            int s1 = __shfl(sv, base | (j + 1));
            u32x4 xv0 = *(const u32x4*)(xb + (long)s0 * H);
            u32x4 ev0 = *(const u32x4*)(ej + (long)(j + 0) * H);
            u32x4 xv1 = *(const u32x4*)(xb + (long)s1 * H);
            u32x4 ev1 = *(const u32x4*)(ej + (long)(j + 1) * H);
            acc8(a, xv0, ev0);
            acc8(b, xv1, ev1);
        }
        if (j < m) {
            int s0 = __shfl(sv, base | j);
            u32x4 xv0 = *(const u32x4*)(xb + (long)s0 * H);
            u32x4 ev0 = *(const u32x4*)(ej + (long)j * H);
            acc8(a, xv0, ev0);
        }
    }
    u32x4 xself = *(const u32x4*)(xb + (long)n * H);
    u32x4 xsrow;
    #pragma unroll
    for (int q = 0; q < 4; q++) {
        float o0 = bf2f(xself[q] & 0xffff) + a[2 * q + 0] + b[2 * q + 0];
        float o1 = bf2f(xself[q] >> 16)    + a[2 * q + 1] + b[2 * q + 1];
        xsrow[q] = bfpack(o0, o1);
    }
    *(uint4*)&sA[r * 136 + fo] = *(uint4*)&xsrow;   // xs row -> LDS (bf16)
    __syncthreads();

    // ---------- conv phase: 16x128 tile, 2 GEMMs ----------
    int w = tid >> 6, quad = lane >> 4, n15 = l16;
    float rb1[2] = { b1[w * 32 + n15], b1[w * 32 + 16 + n15] };
    float rb2[2] = { b2[w * 32 + n15], b2[w * 32 + 16 + n15] };
    // GEMM1 (weights streamed from global/L2 to keep VGPR low)
    f32x4 acc[2];
    acc[0] = (f32x4){0,0,0,0}; acc[1] = (f32x4){0,0,0,0};
    #pragma unroll
    for (int kk = 0; kk < 4; kk++) {
        short8 av = *(const short8*)&sA[n15 * 136 + kk * 32 + quad * 8];
        short8 w0 = pW1[((w * 4 + kk) * 2 + 0) * 64 + lane];
        short8 w1v = pW1[((w * 4 + kk) * 2 + 1) * 64 + lane];
        acc[0] = __builtin_amdgcn_mfma_f32_16x16x32_bf16(av, w0, acc[0], 0, 0, 0);
        acc[1] = __builtin_amdgcn_mfma_f32_16x16x32_bf16(av, w1v, acc[1], 0, 0, 0);
    }
    __syncthreads();   // sA reads done
    #pragma unroll
    for (int nt = 0; nt < 2; nt++) {
        int col = w * 32 + nt * 16 + n15;
        int rb = (quad * 4) * 136 + col;
        u32 p0 = bfpack(fmaxf(acc[nt][0] + rb1[nt], 0.0f),
                        fmaxf(acc[nt][1] + rb1[nt], 0.0f));
        u32 p1 = bfpack(fmaxf(acc[nt][2] + rb1[nt], 0.0f),
                        fmaxf(acc[nt][3] + rb1[nt], 0.0f));
        sA[rb]       = (u16)p0;
        sA[rb + 136] = (u16)(p0 >> 16);
        sA[rb + 272] = (u16)p1;
        sA[rb + 408] = (u16)(p1 >> 16);
    }
    __syncthreads();
    // GEMM2
    acc[0] = (f32x4){0,0,0,0}; acc[1] = (f32x4){0,0,0,0};
    #pragma unroll
    for (int kk = 0; kk < 4; kk++) {
        short8 av = *(const short8*)&sA[n15 * 136 + kk * 32 + quad * 8];
        short8 w0 = pW2[((w * 4 + kk) * 2 + 0) * 64 + lane];
        short8 w1v = pW2[((w * 4 + kk) * 2 + 1) * 64 + lane];
        acc[0] = __builtin_amdgcn_mfma_f32_16x16x32_bf16(av, w0, acc[0], 0, 0, 0);
        acc[1] = __builtin_amdgcn_mfma_f32_16x16x32_bf16(av, w1v, acc[1], 0, 0, 0);
    }
    __syncthreads();   // sA reads done
    #pragma unroll
    for (int nt = 0; nt < 2; nt++) {
        int col = w * 32 + nt * 16 + n15;
        int rb = (quad * 4) * 136 + col;
        u32 p0 = bfpack(fmaxf(acc[nt][0] + rb2[nt], 0.0f),
                        fmaxf(acc[nt][1] + rb2[nt], 0.0f));
        u32 p1 = bfpack(fmaxf(acc[nt][2] + rb2[nt], 0.0f),
                        fmaxf(acc[nt][3] + rb2[nt], 0.0f));
        sA[rb]       = (u16)p0;
        sA[rb + 136] = (u16)(p0 >> 16);
        sA[rb + 272] = (u16)p1;
        sA[rb + 408] = (u16)(p1 >> 16);
    }
    __syncthreads();
    if (!do_pool) {
        // coalesced row store: 16 rows x 16 uint4 chunks = 256 = 1/thread
        int rr = tid >> 4, c8 = (tid & 15) << 3;
        int nn = blockIdx.x * 16 + rr;
        *(uint4*)&x_out[(long)nn * H + c8] = *(const uint4*)&sA[rr * 136 + c8];
    } else {
        // pool epilogue v3: per-block segment partials (no hot-path atomics)
        if (tid < 64) {
            int c2 = tid * 2;
            float s0 = 0.0f, s1 = 0.0f;
            int cur = sBt[0];
            int seg = 0;
            #pragma unroll
            for (int rr = 0; rr < 16; rr++) {
                int bb = sBt[rr];
                if (bb != cur) {
                    if (seg < 4) {
                        long pb = ((long)blockIdx.x * 4 + seg) * H;
                        part_sums[pb + c2]     = s0;
                        part_sums[pb + c2 + 1] = s1;
                    } else {   // overflow (never for this data): fallback
                        atomicAdd(&sums[cur * H + c2],     s0);
                        atomicAdd(&sums[cur * H + c2 + 1], s1);
                    }
                    s0 = s1 = 0.0f; cur = bb; seg++;
                }
                u32 v = *(const u32*)&sA[rr * 136 + c2];
                s0 += bf2f(v & 0xffff);
                s1 += bf2f(v >> 16);
            }
            if (seg < 4) {
                long pb = ((long)blockIdx.x * 4 + seg) * H;
                part_sums[pb + c2]     = s0;
                part_sums[pb + c2 + 1] = s1;
            } else {
                atomicAdd(&sums[cur * H + c2],     s0);
                atomicAdd(&sums[cur * H + c2 + 1], s1);
            }
        } else if (tid == 64) {
            int cur = sBt[0];
            int seg = 0;
            #pragma unroll
            for (int rr = 0; rr < 16; rr++) {
                int bb = sBt[rr];
                if (bb != cur) {
                    if (seg < 4) part_id[blockIdx.x * 4 + seg] = cur;
                    cur = bb; seg++;
                }
            }
            if (seg < 4) part_id[blockIdx.x * 4 + seg] = cur;
            for (int s2 = seg + 1; s2 < 4; s2++) part_id[blockIdx.x * 4 + s2] = -1;
        }
    }
}

// ---- regressor: binary-search node range; reduce segment partials --------
__global__ __launch_bounds__(128) void regressor_kernel(
    const float* __restrict__ sums,          // fallback contributions
    const float* __restrict__ part_sums,
    const int* __restrict__ part_id,
    const int* __restrict__ batch,
    const float* __restrict__ depth,
    const float* __restrict__ w1, const float* __restrict__ b1,
    const float* __restrict__ w2, const float* __restrict__ b2,
    float* __restrict__ out)
{
    __shared__ float s_mean[H];
    __shared__ float s_red[2];
    int b = blockIdx.x;
    int j = threadIdx.x;
    // lower_bound(batch, b) and lower_bound(batch, b+1)
    int lo = 0, hi = N_NODES;
    while (lo < hi) { int mid = (lo + hi) >> 1; if (batch[mid] < b) lo = mid + 1; else hi = mid; }
    int n_start = lo;
    hi = N_NODES;
    while (lo < hi) { int mid = (lo + hi) >> 1; if (batch[mid] < b + 1) lo = mid + 1; else hi = mid; }
    int n_end = lo;
    float acc = sums[b * H + j];
    if (n_end > n_start) {
        int blk0 = n_start >> 4, blk1 = (n_end - 1) >> 4;
        for (int blk = blk0; blk <= blk1; blk++) {
            #pragma unroll
            for (int s = 0; s < 4; s++)
                if (part_id[blk * 4 + s] == b)
                    acc += part_sums[((long)blk * 4 + s) * H + j];
        }
    }
    float c = fmaxf((float)(n_end - n_start), 1.0f);
    s_mean[j] = acc / c;
    __syncthreads();
    float h = b1[j];
    #pragma unroll 8
    for (int k = 0; k < H; k++) h += s_mean[k] * w1[k * H + j];
    h += depth[b] * w1[H * H + j];
    h = fmaxf(h, 0.0f);
    float p = h * w2[j];
    #pragma unroll
    for (int off = 32; off >= 1; off >>= 1) p += __shfl_down(p, off, 64);
    if ((j & 63) == 0) s_red[j >> 6] = p;
    __syncthreads();
    if (j == 0) out[b] = s_red[0] + s_red[1] + b2[0];
}

extern "C" void kernel_launch(void* const* d_in, const int* in_sizes, int n_in,
                              void* d_out, int out_size, void* d_ws, size_t ws_size,
                              hipStream_t stream)
{
    const int*   ids   = (const int*)  d_in[0];
    const int*   eidx  = (const int*)  d_in[1];
    const float* eattr = (const float*)d_in[2];
    const int*   batch = (const int*)  d_in[3];
    const float* depth = (const float*)d_in[4];
    const float* id_w1 = (const float*)d_in[5];
    const float* id_b1 = (const float*)d_in[6];
    const float* id_w2 = (const float*)d_in[7];
    const float* id_b2 = (const float*)d_in[8];
    const float* ed_w1 = (const float*)d_in[9];
    const float* ed_b1 = (const float*)d_in[10];
    const float* ed_w2 = (const float*)d_in[11];
    const float* ed_b2 = (const float*)d_in[12];
    const float* c1_w1 = (const float*)d_in[13];
    const float* c1_b1 = (const float*)d_in[14];
    const float* c1_w2 = (const float*)d_in[15];
    const float* c1_b2 = (const float*)d_in[16];
    const float* c2_w1 = (const float*)d_in[17];
    const float* c2_b1 = (const float*)d_in[18];
    const float* c2_w2 = (const float*)d_in[19];
    const float* c2_b2 = (const float*)d_in[20];
    const float* rg_w1 = (const float*)d_in[21];
    const float* rg_b1 = (const float*)d_in[22];
    const float* rg_w2 = (const float*)d_in[23];
    const float* rg_b2 = (const float*)d_in[24];

    char* ws = (char*)d_ws;
    u16*   e_buf    = (u16*)  (ws);                      // 153,600,000 B (CSR order)
    u16*   x_buf    = (u16*)  (ws + 153600000);          //  25,600,000 B
    u16*   xs_buf   = (u16*)  (ws + 179200000);          //  25,600,000 B (x ping-pong)
    float* sums_buf = (float*)(ws + 204800000);          //     262,144 B (fallback)
    int*   counts   = (int*)  (ws + 205064192);          //     401,408 B
    int*   chunk_sc = (int*)  (ws + 205465600);          //     401,408 B
    int*   bsum_raw = (int*)  (ws + 205867008);          //         512 B
    int*   src_list = (int*)  (ws + 205868032);          //   2,400,000 B
    short8* ed_w1p  = (short8*)(ws + 208268032);         //       8,192 B
    short8* ed_w2p  = (short8*)(ws + 208276224);         //      32,768 B
    short8* c1_w1p  = (short8*)(ws + 208308992);
    short8* c1_w2p  = (short8*)(ws + 208341760);
    short8* c2_w1p  = (short8*)(ws + 208374528);
    short8* c2_w2p  = (short8*)(ws + 208407296);
    short8* id_w2p  = (short8*)(ws + 208440064);
    int*   row_start = counts;            // counts dead after fill; reuse
    u16*   attr_perm = xs_buf;            // dead before gine1 write
    float* part_sums = (float*)x_buf;     // x_buf dead after gine1 (12.8 MB < 25.6)
    int*   part_id   = chunk_sc;          // chunk_sc dead after edge_node (100 KB < 401)

    // zero counts (must precede hist)
    hipMemsetAsync(counts, 0, 401408, stream);

    // pack (0..49) + hist (50..2393) + zero sums (2394..2457)
    const int HIST_BLKS = (N_EDGES + 255) / 256;   // 2344
    pack_hist_kernel<<<50 + HIST_BLKS + 64, 256, 0, stream>>>(
        ed_w1, ed_w2, c1_w1, c1_w2, c2_w1, c2_w2, id_w2,
        ed_w1p, ed_w2p, c1_w1p, c1_w2p, c2_w1p, c2_w2p, id_w2p,
        eidx, counts, (uint4*)sums_buf);

    // scan1 only (98 blocks)
    scan_kernel<<<N_CHUNKS, 256, 0, stream>>>(counts, chunk_sc, bsum_raw);

    // fill (local bsum scan inside)
    fill_kernel<<<(N_EDGES + 255) / 256, 256, 0, stream>>>(
        eidx, chunk_sc, bsum_raw, counts, src_list, eattr, attr_perm);

    // edge MLP (blocks 0..3124, finalize on 0..391) + node MLP (3125..4687)
    edge_node_mfma<<<EDGE_BLKS + NODE_TILES, 256, 0, stream>>>(
        attr_perm, chunk_sc, bsum_raw, row_start,
        ed_w1p, ed_b1, ed_w2p, ed_b2, e_buf,
        ids, id_w1, id_b1, id_w2p, id_b2, x_buf);

    // layer 1 (fused aggregate + conv MLP): x_buf -> xs_buf
    gine_fused<<<6250, 256, 0, stream>>>(row_start, src_list, e_buf, x_buf,
                                         c1_w1p, c1_b1, c1_w2p, c1_b2, xs_buf,
                                         batch, sums_buf, part_sums, part_id, 0);
    // layer 2 (+pool partials): xs_buf -> part_sums/part_id
    gine_fused<<<6250, 256, 0, stream>>>(row_start, src_list, e_buf, xs_buf,
                                         c2_w1p, c2_b1, c2_w2p, c2_b2, x_buf,
                                         batch, sums_buf, part_sums, part_id, 1);

    // regressor (reduces partials; counts via binary search over sorted batch)
    regressor_kernel<<<NB, 128, 0, stream>>>(sums_buf, part_sums, part_id, batch,
                                             depth, rg_w1, rg_b1, rg_w2, rg_b2,
                                             (float*)d_out);
}